// Round 10
// baseline (4184.971 us; speedup 1.0000x reference)
//
#include <hip/hip_runtime.h>

#define NN 100000   // nodes
#define NE 1600000  // edges
#define FD 128      // feature dim (4 heads x 32 ch)
#define NB 391      // ceil(NN/256) dst-buckets
#define CAP 4800    // padded bucket capacity (mean 4096, sigma 64 -> +11 sigma)
#define CHUNK 8192  // edges per k_bucket block -> 196 blocks

typedef __attribute__((ext_vector_type(8))) short bf16x8;
typedef __attribute__((ext_vector_type(4))) float f32x4;

union B8 { bf16x8 v; unsigned int u[4]; };

// ---------------- helpers ----------------

__device__ __forceinline__ unsigned short f2bf(float x) {
    unsigned int u = __float_as_uint(x);
    u += 0x7fffu + ((u >> 16) & 1u);   // round-to-nearest-even
    return (unsigned short)(u >> 16);
}

__device__ __forceinline__ unsigned int pkhi(unsigned int ua, unsigned int ub) {
    return __builtin_amdgcn_perm(ub, ua, 0x07060302);
}

__device__ __forceinline__ void split8(const float4& x0, const float4& x1,
                                       bf16x8& hi, bf16x8& lo) {
    float f[8] = {x0.x, x0.y, x0.z, x0.w, x1.x, x1.y, x1.z, x1.w};
    B8 H, L;
#pragma unroll
    for (int i = 0; i < 4; i++) {
        unsigned int ua = __float_as_uint(f[2 * i]);
        unsigned int ub = __float_as_uint(f[2 * i + 1]);
        H.u[i] = pkhi(ua, ub);
        float ra = f[2 * i]     - __uint_as_float(ua & 0xffff0000u);
        float rb = f[2 * i + 1] - __uint_as_float(ub & 0xffff0000u);
        L.u[i] = pkhi(__float_as_uint(ra), __float_as_uint(rb));
    }
    hi = H.v; lo = L.v;
}

// ---------------- W pre-split + workspace zeroing (one dispatch) ----------------

__global__ void k_wsplit3(const float* __restrict__ W1, const float* __restrict__ W2,
                          const float* __restrict__ W3, unsigned short* __restrict__ Wth,
                          unsigned short* __restrict__ Wtl, int* __restrict__ gcur,
                          float* __restrict__ pooled) {
    int gid = blockIdx.x * 256 + threadIdx.x;  // 0..49151
    if (gid < NB) gcur[gid] = 0;
    if (gid >= 1024 && gid < 1152) pooled[gid - 1024] = 0.f;
    int w = gid >> 14;
    int tid = gid & 16383;
    const float* W = (w == 0) ? W1 : (w == 1) ? W2 : W3;
    int n = tid >> 7, k = tid & 127;
    float val = W[k * 128 + n];
    unsigned short h = f2bf(val);
    float res = val - __uint_as_float((unsigned int)h << 16);
    Wth[gid] = h;
    Wtl[gid] = f2bf(res);
}

// ---------------- bucket scatter into padded per-bucket slots ----------------
// pairs[b*CAP + slot] = src | (dst&255)<<17

__global__ __launch_bounds__(256) void k_bucket(const int* __restrict__ src,
                                                const int* __restrict__ dst,
                                                int* __restrict__ gcur,
                                                unsigned int* __restrict__ pairs) {
    __shared__ int scnt[NB];
    __shared__ int sbase[NB];
    int t = threadIdx.x;
    for (int i = t; i < NB; i += 256) scnt[i] = 0;
    __syncthreads();
    int e0 = blockIdx.x * CHUNK, e1 = min(e0 + CHUNK, NE);
    for (int i = e0 + t; i < e1; i += 256) atomicAdd(&scnt[dst[i] >> 8], 1);
    __syncthreads();
    for (int i = t; i < NB; i += 256) {
        int c = scnt[i];
        sbase[i] = (c > 0) ? (i * CAP + atomicAdd(&gcur[i], c)) : 0;
        scnt[i] = 0;  // reuse as local cursor
    }
    __syncthreads();
    for (int i = e0 + t; i < e1; i += 256) {
        int d = dst[i];
        int b = d >> 8;
        int r = atomicAdd(&scnt[b], 1);
        pairs[sbase[b] + r] = (unsigned int)src[i] | ((unsigned int)(d & 255) << 17);
    }
}

// ---------------- per-bucket counting sort -> padded CSR (off, deg, ssrc) ----------------

__global__ __launch_bounds__(256) void k_bsort(const unsigned int* __restrict__ pairs,
                                               const int* __restrict__ gcur,
                                               int* __restrict__ off,
                                               int* __restrict__ deg,
                                               int* __restrict__ ssrc) {
    __shared__ int hcnt[256];
    __shared__ int cur[256];
    int t = threadIdx.x;
    int b = blockIdx.x;
    int cnt = gcur[b];
    int estart = b * CAP;
    hcnt[t] = 0;
    __syncthreads();
    for (int i = t; i < cnt; i += 256)
        atomicAdd(&hcnt[(pairs[estart + i] >> 17) & 255], 1);
    __syncthreads();
    int v = hcnt[t];
    cur[t] = v;
    __syncthreads();
    for (int o = 1; o < 256; o <<= 1) {
        int x = (t >= o) ? cur[t - o] : 0;
        __syncthreads();
        cur[t] += x;
        __syncthreads();
    }
    int excl = cur[t] - v;
    int node = (b << 8) + t;
    if (node < NN) {
        off[node] = estart + excl;
        deg[node] = v;
    }
    __syncthreads();
    cur[t] = estart + excl;
    __syncthreads();
    for (int i = t; i < cnt; i += 256) {
        unsigned int p = pairs[estart + i];
        int pos = atomicAdd(&cur[(p >> 17) & 255], 1);
        ssrc[pos] = (int)(p & 0x1ffffu);
    }
}

// ---------------- fused GEMM epilogue: bf16 features + el/er scores ----------------

__device__ __forceinline__ void epilogue(f32x4 acc[2][8], int row0, int q, int r, int nrows,
                                         const float* __restrict__ al,
                                         const float* __restrict__ ar,
                                         unsigned short* __restrict__ Fb,
                                         float* __restrict__ el, float* __restrict__ er) {
#pragma unroll
    for (int g = 0; g < 2; g++) {
#pragma unroll
        for (int i = 0; i < 4; i++) {
            int row = row0 + g * 16 + q * 4 + i;
            float elp[4], erp[4];
#pragma unroll
            for (int h = 0; h < 4; h++) { elp[h] = 0.f; erp[h] = 0.f; }
#pragma unroll
            for (int nt = 0; nt < 8; nt++) {
                int h = nt >> 1;
                int c = ((nt & 1) << 4) + r;
                float v = acc[g][nt][i];
                elp[h] = fmaf(v, al[h * 32 + c], elp[h]);
                erp[h] = fmaf(v, ar[h * 32 + c], erp[h]);
            }
#pragma unroll
            for (int o = 1; o < 16; o <<= 1) {
#pragma unroll
                for (int h = 0; h < 4; h++) {
                    elp[h] += __shfl_xor(elp[h], o);
                    erp[h] += __shfl_xor(erp[h], o);
                }
            }
            if (row < nrows) {
#pragma unroll
                for (int nt = 0; nt < 8; nt++)
                    Fb[(size_t)row * FD + nt * 16 + r] = f2bf(acc[g][nt][i]);
                int hh = r & 3;
                float ve = (hh & 2) ? ((hh & 1) ? elp[3] : elp[2]) : ((hh & 1) ? elp[1] : elp[0]);
                float vr = (hh & 2) ? ((hh & 1) ? erp[3] : erp[2]) : ((hh & 1) ? erp[1] : erp[0]);
                if (r < 4) el[row * 4 + hh] = ve;
                else if (r < 8) er[row * 4 + hh] = vr;
            }
        }
    }
}

// ---------------- MFMA GEMM (layer 1): A f32, hi/lo split both sides ----------------

__global__ __launch_bounds__(256) void k_gemm_f32(const float* __restrict__ A,
                                                  const unsigned short* __restrict__ Wth,
                                                  const unsigned short* __restrict__ Wtl,
                                                  unsigned short* __restrict__ Fb, int nrows,
                                                  const float* __restrict__ al,
                                                  const float* __restrict__ ar,
                                                  float* __restrict__ el,
                                                  float* __restrict__ er) {
    int t = threadIdx.x;
    int wave = t >> 6, lane = t & 63;
    int r = lane & 15, q = lane >> 4;
    int row0 = blockIdx.x * 128 + wave * 32;
    int rg0 = row0 + r, rg1 = row0 + 16 + r;

    f32x4 acc[2][8];
#pragma unroll
    for (int g = 0; g < 2; g++)
#pragma unroll
        for (int nt = 0; nt < 8; nt++) acc[g][nt] = (f32x4){0.f, 0.f, 0.f, 0.f};

#pragma unroll
    for (int ks = 0; ks < 4; ks++) {
        int k0 = ks * 32 + q * 8;
        float4 z = make_float4(0.f, 0.f, 0.f, 0.f);
        float4 a0 = z, a1 = z, b0 = z, b1 = z;
        if (rg0 < nrows) {
            const float* pa = A + (size_t)rg0 * FD + k0;
            a0 = *(const float4*)pa;
            a1 = *(const float4*)(pa + 4);
        }
        if (rg1 < nrows) {
            const float* pb = A + (size_t)rg1 * FD + k0;
            b0 = *(const float4*)pb;
            b1 = *(const float4*)(pb + 4);
        }
        bf16x8 ah0, al0, ah1, al1;
        split8(a0, a1, ah0, al0);
        split8(b0, b1, ah1, al1);
#pragma unroll
        for (int nt = 0; nt < 8; nt++) {
            int wo = ((nt * 16 + r) << 7) + k0;
            bf16x8 bh = *(const bf16x8*)(Wth + wo);
            bf16x8 bl = *(const bf16x8*)(Wtl + wo);
            acc[0][nt] = __builtin_amdgcn_mfma_f32_16x16x32_bf16(ah0, bh, acc[0][nt], 0, 0, 0);
            acc[0][nt] = __builtin_amdgcn_mfma_f32_16x16x32_bf16(al0, bh, acc[0][nt], 0, 0, 0);
            acc[0][nt] = __builtin_amdgcn_mfma_f32_16x16x32_bf16(ah0, bl, acc[0][nt], 0, 0, 0);
            acc[1][nt] = __builtin_amdgcn_mfma_f32_16x16x32_bf16(ah1, bh, acc[1][nt], 0, 0, 0);
            acc[1][nt] = __builtin_amdgcn_mfma_f32_16x16x32_bf16(al1, bh, acc[1][nt], 0, 0, 0);
            acc[1][nt] = __builtin_amdgcn_mfma_f32_16x16x32_bf16(ah1, bl, acc[1][nt], 0, 0, 0);
        }
    }
    epilogue(acc, row0, q, r, nrows, al, ar, Fb, el, er);
}

// ---------------- MFMA GEMM (layers 2,3): A bf16, W hi/lo -> 2 MFMAs ----------------

__global__ __launch_bounds__(256) void k_gemm_bf(const unsigned short* __restrict__ A,
                                                 const unsigned short* __restrict__ Wth,
                                                 const unsigned short* __restrict__ Wtl,
                                                 unsigned short* __restrict__ Fb, int nrows,
                                                 const float* __restrict__ al,
                                                 const float* __restrict__ ar,
                                                 float* __restrict__ el,
                                                 float* __restrict__ er) {
    int t = threadIdx.x;
    int wave = t >> 6, lane = t & 63;
    int r = lane & 15, q = lane >> 4;
    int row0 = blockIdx.x * 128 + wave * 32;
    int rg0 = row0 + r, rg1 = row0 + 16 + r;

    f32x4 acc[2][8];
#pragma unroll
    for (int g = 0; g < 2; g++)
#pragma unroll
        for (int nt = 0; nt < 8; nt++) acc[g][nt] = (f32x4){0.f, 0.f, 0.f, 0.f};

#pragma unroll
    for (int ks = 0; ks < 4; ks++) {
        int k0 = ks * 32 + q * 8;
        bf16x8 a0 = {0, 0, 0, 0, 0, 0, 0, 0};
        bf16x8 a1 = {0, 0, 0, 0, 0, 0, 0, 0};
        if (rg0 < nrows) a0 = *(const bf16x8*)(A + (size_t)rg0 * FD + k0);
        if (rg1 < nrows) a1 = *(const bf16x8*)(A + (size_t)rg1 * FD + k0);
#pragma unroll
        for (int nt = 0; nt < 8; nt++) {
            int wo = ((nt * 16 + r) << 7) + k0;
            bf16x8 bh = *(const bf16x8*)(Wth + wo);
            bf16x8 bl = *(const bf16x8*)(Wtl + wo);
            acc[0][nt] = __builtin_amdgcn_mfma_f32_16x16x32_bf16(a0, bh, acc[0][nt], 0, 0, 0);
            acc[0][nt] = __builtin_amdgcn_mfma_f32_16x16x32_bf16(a0, bl, acc[0][nt], 0, 0, 0);
            acc[1][nt] = __builtin_amdgcn_mfma_f32_16x16x32_bf16(a1, bh, acc[1][nt], 0, 0, 0);
            acc[1][nt] = __builtin_amdgcn_mfma_f32_16x16x32_bf16(a1, bl, acc[1][nt], 0, 0, 0);
        }
    }
    epilogue(acc, row0, q, r, nrows, al, ar, Fb, el, er);
}

// ---------------- aggregation: one wave per dst node, single pass ----------------
// POOL=0: write packed-bf16 H rows. POOL=1 (last layer): atomicMax into pooled[128].

template <int POOL>
__global__ __launch_bounds__(256) void k_agg(const unsigned short* __restrict__ Fb,
                                             const float* __restrict__ el,
                                             const float* __restrict__ er,
                                             const int* __restrict__ off,
                                             const int* __restrict__ deg_,
                                             const int* __restrict__ ssrc,
                                             unsigned int* __restrict__ outp,
                                             float* __restrict__ pooled) {
    int wave = threadIdx.x >> 6;
    int lane = threadIdx.x & 63;
    int d = blockIdx.x * 4 + wave;
    if (d >= NN) return;
    int start = off[d];
    int deg = deg_[d];
    float2 acc = make_float2(0.f, 0.f);
    if (deg > 0) {
        int h = lane & 3;
        int eloc = lane >> 2;
        int hsel = lane >> 4;  // head owning channels {2*lane, 2*lane+1}
        float er_h = er[d * 4 + h];
        float s = 0.f;
        for (int base = 0; base < deg; base += 16) {
            int i = base + eloc;
            float a = 0.f;
            int sid = 0;  // invalid lanes -> row 0 with weight 0 (L1-hot, harmless)
            if (i < deg) {
                sid = ssrc[start + i];
                float v = el[sid * 4 + h] + er_h;
                float e = v > 0.f ? v : 0.2f * v;
                a = __expf(e);
            }
            s += a;
            int sids[16];
            float a16[16];
#pragma unroll
            for (int j = 0; j < 16; j++) {
                sids[j] = __builtin_amdgcn_readlane(sid, 4 * j);
                a16[j] = __shfl(a, 4 * j + hsel, 64);
            }
            unsigned int u[16];
#pragma unroll
            for (int j = 0; j < 16; j++) {
                u[j] = *(const unsigned int*)(Fb + (size_t)sids[j] * FD + lane * 2);
            }
#pragma unroll
            for (int j = 0; j < 16; j++) {
                acc.x = fmaf(a16[j], __uint_as_float(u[j] << 16), acc.x);
                acc.y = fmaf(a16[j], __uint_as_float(u[j] & 0xffff0000u), acc.y);
            }
        }
        for (int o = 4; o < 64; o <<= 1) s += __shfl_xor(s, o);
        float inv = 1.f / __shfl(s, hsel, 64);
        acc.x *= inv;
        acc.y *= inv;
    }
    acc.x = fmaxf(acc.x, 0.f);  // relu
    acc.y = fmaxf(acc.y, 0.f);
    if (POOL) {
        atomicMax((int*)&pooled[lane * 2], __float_as_int(acc.x));
        atomicMax((int*)&pooled[lane * 2 + 1], __float_as_int(acc.y));
    } else {
        unsigned int pk = ((unsigned int)f2bf(acc.y) << 16) | f2bf(acc.x);
        outp[(size_t)d * 64 + lane] = pk;
    }
}

// ---------------- final FC + softmax ----------------

__global__ void k_final(const float* __restrict__ pooled, const float* __restrict__ Wfc,
                        const float* __restrict__ bfc, float* __restrict__ outp) {
    int lane = threadIdx.x;
    int j = lane & 7;
    int kk = lane >> 3;
    float partial = 0.f;
    for (int k = kk * 16; k < kk * 16 + 16; ++k) partial += pooled[k] * Wfc[k * 8 + j];
    for (int o = 8; o < 64; o <<= 1) partial += __shfl_xor(partial, o);
    float logit = partial + bfc[j];
    float mx = logit;
    for (int o = 1; o < 8; o <<= 1) mx = fmaxf(mx, __shfl_xor(mx, o));
    float ex = __expf(logit - mx);
    float sm = ex;
    for (int o = 1; o < 8; o <<= 1) sm += __shfl_xor(sm, o);
    if (lane < 8) outp[lane] = ex / sm;
}

// ---------------- launch ----------------

extern "C" void kernel_launch(void* const* d_in, const int* in_sizes, int n_in,
                              void* d_out, int out_size, void* d_ws, size_t ws_size,
                              hipStream_t stream) {
    const float* x   = (const float*)d_in[0];
    const int*   src = (const int*)d_in[1];
    const int*   dst = (const int*)d_in[2];
    const float* W1  = (const float*)d_in[3];
    const float* al1 = (const float*)d_in[4];
    const float* ar1 = (const float*)d_in[5];
    const float* W2  = (const float*)d_in[6];
    const float* al2 = (const float*)d_in[7];
    const float* ar2 = (const float*)d_in[8];
    const float* W3  = (const float*)d_in[9];
    const float* al3 = (const float*)d_in[10];
    const float* ar3 = (const float*)d_in[11];
    const float* Wfc = (const float*)d_in[12];
    const float* bfc = (const float*)d_in[13];
    float* out = (float*)d_out;

    char* p = (char*)d_ws;
    auto alloc = [&](size_t bytes) {
        char* r = p;
        p += (bytes + 255) & ~(size_t)255;
        return r;
    };
    unsigned short* Fb = (unsigned short*)alloc((size_t)NN * FD * 2);
    unsigned int*   Hb = (unsigned int*)alloc((size_t)NN * FD * 2);  // bf16x2-packed H
    float* el     = (float*)alloc((size_t)NN * 4 * 4);
    float* er     = (float*)alloc((size_t)NN * 4 * 4);
    int*   off    = (int*)alloc((size_t)NN * 4);
    int*   deg    = (int*)alloc((size_t)NN * 4);
    int*   ssrc   = (int*)alloc((size_t)NB * CAP * 4);
    unsigned int* pairs = (unsigned int*)alloc((size_t)NB * CAP * 4);
    int*   gcur   = (int*)alloc((size_t)NB * 4);
    float* pooled = (float*)alloc(128 * 4);
    unsigned short* Wth = (unsigned short*)alloc(3 * 16384 * 2);
    unsigned short* Wtl = (unsigned short*)alloc(3 * 16384 * 2);

    const int GB = (NN + 127) / 128;
    const int AB = (NN + 3) / 4;
    const int BB = (NE + CHUNK - 1) / CHUNK;  // 196

    k_wsplit3<<<192, 256, 0, stream>>>(W1, W2, W3, Wth, Wtl, gcur, pooled);
    k_bucket<<<BB, 256, 0, stream>>>(src, dst, gcur, pairs);
    k_bsort<<<NB, 256, 0, stream>>>(pairs, gcur, off, deg, ssrc);

    // layer 1
    k_gemm_f32<<<GB, 256, 0, stream>>>(x, Wth, Wtl, Fb, NN, al1, ar1, el, er);
    k_agg<0><<<AB, 256, 0, stream>>>(Fb, el, er, off, deg, ssrc, Hb, pooled);
    // layer 2
    k_gemm_bf<<<GB, 256, 0, stream>>>((const unsigned short*)Hb, Wth + 16384, Wtl + 16384, Fb, NN, al2, ar2, el, er);
    k_agg<0><<<AB, 256, 0, stream>>>(Fb, el, er, off, deg, ssrc, Hb, pooled);
    // layer 3: aggregate + fused graph max-pool
    k_gemm_bf<<<GB, 256, 0, stream>>>((const unsigned short*)Hb, Wth + 32768, Wtl + 32768, Fb, NN, al3, ar3, el, er);
    k_agg<1><<<AB, 256, 0, stream>>>(Fb, el, er, off, deg, ssrc, Hb, pooled);

    k_final<<<1, 64, 0, stream>>>(pooled, Wfc, bfc, out);
}

// Round 11
// 577.813 us; speedup vs baseline: 7.2428x; 7.2428x over previous
//
#include <hip/hip_runtime.h>

#define NN 100000   // nodes
#define NE 1600000  // edges
#define FD 128      // feature dim (4 heads x 32 ch)
#define NB 391      // ceil(NN/256) dst-buckets
#define CAP 4800    // padded bucket capacity (mean 4096, sigma 64 -> +11 sigma)
#define CHUNK 8192  // edges per k_bucket block -> 196 blocks

typedef __attribute__((ext_vector_type(8))) short bf16x8;
typedef __attribute__((ext_vector_type(4))) float f32x4;

union B8 { bf16x8 v; unsigned int u[4]; };

// ---------------- helpers ----------------

__device__ __forceinline__ unsigned short f2bf(float x) {
    unsigned int u = __float_as_uint(x);
    u += 0x7fffu + ((u >> 16) & 1u);   // round-to-nearest-even
    return (unsigned short)(u >> 16);
}

__device__ __forceinline__ unsigned int pkhi(unsigned int ua, unsigned int ub) {
    return __builtin_amdgcn_perm(ub, ua, 0x07060302);
}

__device__ __forceinline__ void split8(const float4& x0, const float4& x1,
                                       bf16x8& hi, bf16x8& lo) {
    float f[8] = {x0.x, x0.y, x0.z, x0.w, x1.x, x1.y, x1.z, x1.w};
    B8 H, L;
#pragma unroll
    for (int i = 0; i < 4; i++) {
        unsigned int ua = __float_as_uint(f[2 * i]);
        unsigned int ub = __float_as_uint(f[2 * i + 1]);
        H.u[i] = pkhi(ua, ub);
        float ra = f[2 * i]     - __uint_as_float(ua & 0xffff0000u);
        float rb = f[2 * i + 1] - __uint_as_float(ub & 0xffff0000u);
        L.u[i] = pkhi(__float_as_uint(ra), __float_as_uint(rb));
    }
    hi = H.v; lo = L.v;
}

// ---------------- W pre-split + workspace zeroing (one dispatch) ----------------

__global__ void k_wsplit3(const float* __restrict__ W1, const float* __restrict__ W2,
                          const float* __restrict__ W3, unsigned short* __restrict__ Wth,
                          unsigned short* __restrict__ Wtl, int* __restrict__ gcur,
                          float* __restrict__ pooled) {
    int gid = blockIdx.x * 256 + threadIdx.x;  // 0..49151
    if (gid < NB) gcur[gid] = 0;
    if (gid >= 1024 && gid < 1152) pooled[gid - 1024] = 0.f;
    int w = gid >> 14;
    int tid = gid & 16383;
    const float* W = (w == 0) ? W1 : (w == 1) ? W2 : W3;
    int n = tid >> 7, k = tid & 127;
    float val = W[k * 128 + n];
    unsigned short h = f2bf(val);
    float res = val - __uint_as_float((unsigned int)h << 16);
    Wth[gid] = h;
    Wtl[gid] = f2bf(res);
}

// ---------------- bucket scatter into padded per-bucket slots ----------------
// pairs[b*CAP + slot] = src | (dst&255)<<17

__global__ __launch_bounds__(256) void k_bucket(const int* __restrict__ src,
                                                const int* __restrict__ dst,
                                                int* __restrict__ gcur,
                                                unsigned int* __restrict__ pairs) {
    __shared__ int scnt[NB];
    __shared__ int sbase[NB];
    int t = threadIdx.x;
    for (int i = t; i < NB; i += 256) scnt[i] = 0;
    __syncthreads();
    int e0 = blockIdx.x * CHUNK, e1 = min(e0 + CHUNK, NE);
    for (int i = e0 + t; i < e1; i += 256) atomicAdd(&scnt[dst[i] >> 8], 1);
    __syncthreads();
    for (int i = t; i < NB; i += 256) {
        int c = scnt[i];
        sbase[i] = (c > 0) ? (i * CAP + atomicAdd(&gcur[i], c)) : 0;
        scnt[i] = 0;  // reuse as local cursor
    }
    __syncthreads();
    for (int i = e0 + t; i < e1; i += 256) {
        int d = dst[i];
        int b = d >> 8;
        int r = atomicAdd(&scnt[b], 1);
        pairs[sbase[b] + r] = (unsigned int)src[i] | ((unsigned int)(d & 255) << 17);
    }
}

// ---------------- per-bucket counting sort -> padded CSR (off, deg, ssrc) ----------------

__global__ __launch_bounds__(256) void k_bsort(const unsigned int* __restrict__ pairs,
                                               const int* __restrict__ gcur,
                                               int* __restrict__ off,
                                               int* __restrict__ deg,
                                               int* __restrict__ ssrc) {
    __shared__ int hcnt[256];
    __shared__ int cur[256];
    int t = threadIdx.x;
    int b = blockIdx.x;
    int cnt = gcur[b];
    int estart = b * CAP;
    hcnt[t] = 0;
    __syncthreads();
    for (int i = t; i < cnt; i += 256)
        atomicAdd(&hcnt[(pairs[estart + i] >> 17) & 255], 1);
    __syncthreads();
    int v = hcnt[t];
    cur[t] = v;
    __syncthreads();
    for (int o = 1; o < 256; o <<= 1) {
        int x = (t >= o) ? cur[t - o] : 0;
        __syncthreads();
        cur[t] += x;
        __syncthreads();
    }
    int excl = cur[t] - v;
    int node = (b << 8) + t;
    if (node < NN) {
        off[node] = estart + excl;
        deg[node] = v;
    }
    __syncthreads();
    cur[t] = estart + excl;
    __syncthreads();
    for (int i = t; i < cnt; i += 256) {
        unsigned int p = pairs[estart + i];
        int pos = atomicAdd(&cur[(p >> 17) & 255], 1);
        ssrc[pos] = (int)(p & 0x1ffffu);
    }
}

// ---------------- fused GEMM epilogue: bf16 features + el/er scores ----------------

__device__ __forceinline__ void epilogue(f32x4 acc[2][8], int row0, int q, int r, int nrows,
                                         const float* __restrict__ al,
                                         const float* __restrict__ ar,
                                         unsigned short* __restrict__ Fb,
                                         float* __restrict__ el, float* __restrict__ er) {
#pragma unroll
    for (int g = 0; g < 2; g++) {
#pragma unroll
        for (int i = 0; i < 4; i++) {
            int row = row0 + g * 16 + q * 4 + i;
            float elp[4], erp[4];
#pragma unroll
            for (int h = 0; h < 4; h++) { elp[h] = 0.f; erp[h] = 0.f; }
#pragma unroll
            for (int nt = 0; nt < 8; nt++) {
                int h = nt >> 1;
                int c = ((nt & 1) << 4) + r;
                float v = acc[g][nt][i];
                elp[h] = fmaf(v, al[h * 32 + c], elp[h]);
                erp[h] = fmaf(v, ar[h * 32 + c], erp[h]);
            }
#pragma unroll
            for (int o = 1; o < 16; o <<= 1) {
#pragma unroll
                for (int h = 0; h < 4; h++) {
                    elp[h] += __shfl_xor(elp[h], o);
                    erp[h] += __shfl_xor(erp[h], o);
                }
            }
            if (row < nrows) {
#pragma unroll
                for (int nt = 0; nt < 8; nt++)
                    Fb[(size_t)row * FD + nt * 16 + r] = f2bf(acc[g][nt][i]);
                int hh = r & 3;
                float ve = (hh & 2) ? ((hh & 1) ? elp[3] : elp[2]) : ((hh & 1) ? elp[1] : elp[0]);
                float vr = (hh & 2) ? ((hh & 1) ? erp[3] : erp[2]) : ((hh & 1) ? erp[1] : erp[0]);
                if (r < 4) el[row * 4 + hh] = ve;
                else if (r < 8) er[row * 4 + hh] = vr;
            }
        }
    }
}

// ---------------- MFMA GEMM (layer 1): A f32, hi/lo split both sides ----------------

__global__ __launch_bounds__(256) void k_gemm_f32(const float* __restrict__ A,
                                                  const unsigned short* __restrict__ Wth,
                                                  const unsigned short* __restrict__ Wtl,
                                                  unsigned short* __restrict__ Fb, int nrows,
                                                  const float* __restrict__ al,
                                                  const float* __restrict__ ar,
                                                  float* __restrict__ el,
                                                  float* __restrict__ er) {
    int t = threadIdx.x;
    int wave = t >> 6, lane = t & 63;
    int r = lane & 15, q = lane >> 4;
    int row0 = blockIdx.x * 128 + wave * 32;
    int rg0 = row0 + r, rg1 = row0 + 16 + r;

    f32x4 acc[2][8];
#pragma unroll
    for (int g = 0; g < 2; g++)
#pragma unroll
        for (int nt = 0; nt < 8; nt++) acc[g][nt] = (f32x4){0.f, 0.f, 0.f, 0.f};

#pragma unroll
    for (int ks = 0; ks < 4; ks++) {
        int k0 = ks * 32 + q * 8;
        float4 z = make_float4(0.f, 0.f, 0.f, 0.f);
        float4 a0 = z, a1 = z, b0 = z, b1 = z;
        if (rg0 < nrows) {
            const float* pa = A + (size_t)rg0 * FD + k0;
            a0 = *(const float4*)pa;
            a1 = *(const float4*)(pa + 4);
        }
        if (rg1 < nrows) {
            const float* pb = A + (size_t)rg1 * FD + k0;
            b0 = *(const float4*)pb;
            b1 = *(const float4*)(pb + 4);
        }
        bf16x8 ah0, al0, ah1, al1;
        split8(a0, a1, ah0, al0);
        split8(b0, b1, ah1, al1);
#pragma unroll
        for (int nt = 0; nt < 8; nt++) {
            int wo = ((nt * 16 + r) << 7) + k0;
            bf16x8 bh = *(const bf16x8*)(Wth + wo);
            bf16x8 bl = *(const bf16x8*)(Wtl + wo);
            acc[0][nt] = __builtin_amdgcn_mfma_f32_16x16x32_bf16(ah0, bh, acc[0][nt], 0, 0, 0);
            acc[0][nt] = __builtin_amdgcn_mfma_f32_16x16x32_bf16(al0, bh, acc[0][nt], 0, 0, 0);
            acc[0][nt] = __builtin_amdgcn_mfma_f32_16x16x32_bf16(ah0, bl, acc[0][nt], 0, 0, 0);
            acc[1][nt] = __builtin_amdgcn_mfma_f32_16x16x32_bf16(ah1, bh, acc[1][nt], 0, 0, 0);
            acc[1][nt] = __builtin_amdgcn_mfma_f32_16x16x32_bf16(al1, bh, acc[1][nt], 0, 0, 0);
            acc[1][nt] = __builtin_amdgcn_mfma_f32_16x16x32_bf16(ah1, bl, acc[1][nt], 0, 0, 0);
        }
    }
    epilogue(acc, row0, q, r, nrows, al, ar, Fb, el, er);
}

// ---------------- MFMA GEMM (layers 2,3): A bf16, W hi/lo -> 2 MFMAs ----------------

__global__ __launch_bounds__(256) void k_gemm_bf(const unsigned short* __restrict__ A,
                                                 const unsigned short* __restrict__ Wth,
                                                 const unsigned short* __restrict__ Wtl,
                                                 unsigned short* __restrict__ Fb, int nrows,
                                                 const float* __restrict__ al,
                                                 const float* __restrict__ ar,
                                                 float* __restrict__ el,
                                                 float* __restrict__ er) {
    int t = threadIdx.x;
    int wave = t >> 6, lane = t & 63;
    int r = lane & 15, q = lane >> 4;
    int row0 = blockIdx.x * 128 + wave * 32;
    int rg0 = row0 + r, rg1 = row0 + 16 + r;

    f32x4 acc[2][8];
#pragma unroll
    for (int g = 0; g < 2; g++)
#pragma unroll
        for (int nt = 0; nt < 8; nt++) acc[g][nt] = (f32x4){0.f, 0.f, 0.f, 0.f};

#pragma unroll
    for (int ks = 0; ks < 4; ks++) {
        int k0 = ks * 32 + q * 8;
        bf16x8 a0 = {0, 0, 0, 0, 0, 0, 0, 0};
        bf16x8 a1 = {0, 0, 0, 0, 0, 0, 0, 0};
        if (rg0 < nrows) a0 = *(const bf16x8*)(A + (size_t)rg0 * FD + k0);
        if (rg1 < nrows) a1 = *(const bf16x8*)(A + (size_t)rg1 * FD + k0);
#pragma unroll
        for (int nt = 0; nt < 8; nt++) {
            int wo = ((nt * 16 + r) << 7) + k0;
            bf16x8 bh = *(const bf16x8*)(Wth + wo);
            bf16x8 bl = *(const bf16x8*)(Wtl + wo);
            acc[0][nt] = __builtin_amdgcn_mfma_f32_16x16x32_bf16(a0, bh, acc[0][nt], 0, 0, 0);
            acc[0][nt] = __builtin_amdgcn_mfma_f32_16x16x32_bf16(a0, bl, acc[0][nt], 0, 0, 0);
            acc[1][nt] = __builtin_amdgcn_mfma_f32_16x16x32_bf16(a1, bh, acc[1][nt], 0, 0, 0);
            acc[1][nt] = __builtin_amdgcn_mfma_f32_16x16x32_bf16(a1, bl, acc[1][nt], 0, 0, 0);
        }
    }
    epilogue(acc, row0, q, r, nrows, al, ar, Fb, el, er);
}

// ---------------- aggregation: one wave per dst node, single pass ----------------

__global__ __launch_bounds__(256) void k_agg(const unsigned short* __restrict__ Fb,
                                             const float* __restrict__ el,
                                             const float* __restrict__ er,
                                             const int* __restrict__ off,
                                             const int* __restrict__ deg_,
                                             const int* __restrict__ ssrc,
                                             unsigned int* __restrict__ outp) {
    int wave = threadIdx.x >> 6;
    int lane = threadIdx.x & 63;
    int d = blockIdx.x * 4 + wave;
    if (d >= NN) return;
    int start = off[d];
    int deg = deg_[d];
    float2 acc = make_float2(0.f, 0.f);
    if (deg > 0) {
        int h = lane & 3;
        int eloc = lane >> 2;
        int hsel = lane >> 4;  // head owning channels {2*lane, 2*lane+1}
        float er_h = er[d * 4 + h];
        float s = 0.f;
        for (int base = 0; base < deg; base += 16) {
            int i = base + eloc;
            float a = 0.f;
            int sid = 0;  // invalid lanes -> row 0 with weight 0 (L1-hot, harmless)
            if (i < deg) {
                sid = ssrc[start + i];
                float v = el[sid * 4 + h] + er_h;
                float e = v > 0.f ? v : 0.2f * v;
                a = __expf(e);
            }
            s += a;
            int sids[16];
            float a16[16];
#pragma unroll
            for (int j = 0; j < 16; j++) {
                sids[j] = __builtin_amdgcn_readlane(sid, 4 * j);
                a16[j] = __shfl(a, 4 * j + hsel, 64);
            }
            unsigned int u[16];
#pragma unroll
            for (int j = 0; j < 16; j++) {
                u[j] = *(const unsigned int*)(Fb + (size_t)sids[j] * FD + lane * 2);
            }
#pragma unroll
            for (int j = 0; j < 16; j++) {
                acc.x = fmaf(a16[j], __uint_as_float(u[j] << 16), acc.x);
                acc.y = fmaf(a16[j], __uint_as_float(u[j] & 0xffff0000u), acc.y);
            }
        }
        for (int o = 4; o < 64; o <<= 1) s += __shfl_xor(s, o);
        float inv = 1.f / __shfl(s, hsel, 64);
        acc.x *= inv;
        acc.y *= inv;
    }
    acc.x = fmaxf(acc.x, 0.f);  // relu
    acc.y = fmaxf(acc.y, 0.f);
    unsigned int pk = ((unsigned int)f2bf(acc.y) << 16) | f2bf(acc.x);
    outp[(size_t)d * 64 + lane] = pk;
}

// ---------------- graph max-pool over nodes (bf16 H, channel-pair loads) ----------------
// 512 segments x (serial max over ~196 rows) -> 65k atomics on 128 addrs (~512-deep): OK.

__global__ void k_pool(const unsigned int* __restrict__ Hb, float* __restrict__ pooled) {
    int t = threadIdx.x;
    int lane = t & 63;           // channel pair {2*lane, 2*lane+1}
    int walker = t >> 6;
    int seg = blockIdx.x * 4 + walker;   // 512 segments over nodes
    const int NSEG = 512;
    int rpn = (NN + NSEG - 1) / NSEG;    // 196
    int r0 = seg * rpn;
    int r1 = min(NN, r0 + rpn);
    float mx = 0.f, my = 0.f;            // post-relu values >= 0
    for (int r = r0; r < r1; ++r) {
        unsigned int u = Hb[(size_t)r * 64 + lane];
        mx = fmaxf(mx, __uint_as_float(u << 16));
        my = fmaxf(my, __uint_as_float(u & 0xffff0000u));
    }
    atomicMax((int*)&pooled[lane * 2], __float_as_int(mx));
    atomicMax((int*)&pooled[lane * 2 + 1], __float_as_int(my));
}

// ---------------- final FC + softmax ----------------

__global__ void k_final(const float* __restrict__ pooled, const float* __restrict__ Wfc,
                        const float* __restrict__ bfc, float* __restrict__ outp) {
    int lane = threadIdx.x;
    int j = lane & 7;
    int kk = lane >> 3;
    float partial = 0.f;
    for (int k = kk * 16; k < kk * 16 + 16; ++k) partial += pooled[k] * Wfc[k * 8 + j];
    for (int o = 8; o < 64; o <<= 1) partial += __shfl_xor(partial, o);
    float logit = partial + bfc[j];
    float mx = logit;
    for (int o = 1; o < 8; o <<= 1) mx = fmaxf(mx, __shfl_xor(mx, o));
    float ex = __expf(logit - mx);
    float sm = ex;
    for (int o = 1; o < 8; o <<= 1) sm += __shfl_xor(sm, o);
    if (lane < 8) outp[lane] = ex / sm;
}

// ---------------- launch ----------------

extern "C" void kernel_launch(void* const* d_in, const int* in_sizes, int n_in,
                              void* d_out, int out_size, void* d_ws, size_t ws_size,
                              hipStream_t stream) {
    const float* x   = (const float*)d_in[0];
    const int*   src = (const int*)d_in[1];
    const int*   dst = (const int*)d_in[2];
    const float* W1  = (const float*)d_in[3];
    const float* al1 = (const float*)d_in[4];
    const float* ar1 = (const float*)d_in[5];
    const float* W2  = (const float*)d_in[6];
    const float* al2 = (const float*)d_in[7];
    const float* ar2 = (const float*)d_in[8];
    const float* W3  = (const float*)d_in[9];
    const float* al3 = (const float*)d_in[10];
    const float* ar3 = (const float*)d_in[11];
    const float* Wfc = (const float*)d_in[12];
    const float* bfc = (const float*)d_in[13];
    float* out = (float*)d_out;

    char* p = (char*)d_ws;
    auto alloc = [&](size_t bytes) {
        char* r = p;
        p += (bytes + 255) & ~(size_t)255;
        return r;
    };
    unsigned short* Fb = (unsigned short*)alloc((size_t)NN * FD * 2);
    unsigned int*   Hb = (unsigned int*)alloc((size_t)NN * FD * 2);  // bf16x2-packed H
    float* el     = (float*)alloc((size_t)NN * 4 * 4);
    float* er     = (float*)alloc((size_t)NN * 4 * 4);
    int*   off    = (int*)alloc((size_t)NN * 4);
    int*   deg    = (int*)alloc((size_t)NN * 4);
    int*   ssrc   = (int*)alloc((size_t)NB * CAP * 4);
    unsigned int* pairs = (unsigned int*)alloc((size_t)NB * CAP * 4);
    int*   gcur   = (int*)alloc((size_t)NB * 4);
    float* pooled = (float*)alloc(128 * 4);
    unsigned short* Wth = (unsigned short*)alloc(3 * 16384 * 2);
    unsigned short* Wtl = (unsigned short*)alloc(3 * 16384 * 2);

    const int GB = (NN + 127) / 128;
    const int AB = (NN + 3) / 4;
    const int BB = (NE + CHUNK - 1) / CHUNK;  // 196

    k_wsplit3<<<192, 256, 0, stream>>>(W1, W2, W3, Wth, Wtl, gcur, pooled);
    k_bucket<<<BB, 256, 0, stream>>>(src, dst, gcur, pairs);
    k_bsort<<<NB, 256, 0, stream>>>(pairs, gcur, off, deg, ssrc);

    // layer 1
    k_gemm_f32<<<GB, 256, 0, stream>>>(x, Wth, Wtl, Fb, NN, al1, ar1, el, er);
    k_agg<<<AB, 256, 0, stream>>>(Fb, el, er, off, deg, ssrc, Hb);
    // layer 2
    k_gemm_bf<<<GB, 256, 0, stream>>>((const unsigned short*)Hb, Wth + 16384, Wtl + 16384, Fb, NN, al2, ar2, el, er);
    k_agg<<<AB, 256, 0, stream>>>(Fb, el, er, off, deg, ssrc, Hb);
    // layer 3
    k_gemm_bf<<<GB, 256, 0, stream>>>((const unsigned short*)Hb, Wth + 32768, Wtl + 32768, Fb, NN, al3, ar3, el, er);
    k_agg<<<AB, 256, 0, stream>>>(Fb, el, er, off, deg, ssrc, Hb);

    k_pool<<<128, 256, 0, stream>>>(Hb, pooled);
    k_final<<<1, 64, 0, stream>>>(pooled, Wfc, bfc, out);
}

// Round 12
// 575.268 us; speedup vs baseline: 7.2748x; 1.0044x over previous
//
#include <hip/hip_runtime.h>

#define NN 100000   // nodes
#define NE 1600000  // edges
#define FD 128      // feature dim (4 heads x 32 ch)
#define NB 391      // ceil(NN/256) dst-buckets
#define CAP 4800    // padded bucket capacity (mean 4096, sigma 64 -> +11 sigma)
#define CHUNK 8192  // edges per k_bucket block -> 196 blocks
#define GB 782      // gemm tiles (128 rows each)

typedef __attribute__((ext_vector_type(8))) short bf16x8;
typedef __attribute__((ext_vector_type(4))) float f32x4;

union B8 { bf16x8 v; unsigned int u[4]; };

// ---------------- helpers ----------------

__device__ __forceinline__ unsigned short f2bf(float x) {
    unsigned int u = __float_as_uint(x);
    u += 0x7fffu + ((u >> 16) & 1u);   // round-to-nearest-even
    return (unsigned short)(u >> 16);
}

__device__ __forceinline__ unsigned int pkhi(unsigned int ua, unsigned int ub) {
    return __builtin_amdgcn_perm(ub, ua, 0x07060302);
}

__device__ __forceinline__ void split8(const float4& x0, const float4& x1,
                                       bf16x8& hi, bf16x8& lo) {
    float f[8] = {x0.x, x0.y, x0.z, x0.w, x1.x, x1.y, x1.z, x1.w};
    B8 H, L;
#pragma unroll
    for (int i = 0; i < 4; i++) {
        unsigned int ua = __float_as_uint(f[2 * i]);
        unsigned int ub = __float_as_uint(f[2 * i + 1]);
        H.u[i] = pkhi(ua, ub);
        float ra = f[2 * i]     - __uint_as_float(ua & 0xffff0000u);
        float rb = f[2 * i + 1] - __uint_as_float(ub & 0xffff0000u);
        L.u[i] = pkhi(__float_as_uint(ra), __float_as_uint(rb));
    }
    hi = H.v; lo = L.v;
}

// ---------------- W pre-split + workspace zeroing (one dispatch) ----------------

__global__ void k_wsplit3(const float* __restrict__ W1, const float* __restrict__ W2,
                          const float* __restrict__ W3, unsigned short* __restrict__ Wth,
                          unsigned short* __restrict__ Wtl, int* __restrict__ gcur,
                          float* __restrict__ pooled, int* __restrict__ done) {
    int gid = blockIdx.x * 256 + threadIdx.x;  // 0..49151
    if (gid < NB) gcur[gid] = 0;
    if (gid >= 1024 && gid < 1152) pooled[gid - 1024] = 0.f;
    if (gid == 1152) *done = 0;
    int w = gid >> 14;
    int tid = gid & 16383;
    const float* W = (w == 0) ? W1 : (w == 1) ? W2 : W3;
    int n = tid >> 7, k = tid & 127;
    float val = W[k * 128 + n];
    unsigned short h = f2bf(val);
    float res = val - __uint_as_float((unsigned int)h << 16);
    Wth[gid] = h;
    Wtl[gid] = f2bf(res);
}

// ---------------- bucket scatter into padded per-bucket slots ----------------
// pairs[b*CAP + slot] = src | (dst&255)<<17

__global__ __launch_bounds__(256) void k_bucket(const int* __restrict__ src,
                                                const int* __restrict__ dst,
                                                int* __restrict__ gcur,
                                                unsigned int* __restrict__ pairs) {
    __shared__ int scnt[NB];
    __shared__ int sbase[NB];
    int t = threadIdx.x;
    for (int i = t; i < NB; i += 256) scnt[i] = 0;
    __syncthreads();
    int e0 = blockIdx.x * CHUNK, e1 = min(e0 + CHUNK, NE);
    for (int i = e0 + t; i < e1; i += 256) atomicAdd(&scnt[dst[i] >> 8], 1);
    __syncthreads();
    for (int i = t; i < NB; i += 256) {
        int c = scnt[i];
        sbase[i] = (c > 0) ? (i * CAP + atomicAdd(&gcur[i], c)) : 0;
        scnt[i] = 0;  // reuse as local cursor
    }
    __syncthreads();
    for (int i = e0 + t; i < e1; i += 256) {
        int d = dst[i];
        int b = d >> 8;
        int r = atomicAdd(&scnt[b], 1);
        pairs[sbase[b] + r] = (unsigned int)src[i] | ((unsigned int)(d & 255) << 17);
    }
}

// ---------------- per-bucket counting sort body ----------------

__device__ void bsort_body(int b, const unsigned int* __restrict__ pairs,
                           const int* __restrict__ gcur, int* __restrict__ off,
                           int* __restrict__ deg, int* __restrict__ ssrc) {
    __shared__ int hcnt[256];
    __shared__ int cur[256];
    int t = threadIdx.x;
    int cnt = gcur[b];
    int estart = b * CAP;
    hcnt[t] = 0;
    __syncthreads();
    for (int i = t; i < cnt; i += 256)
        atomicAdd(&hcnt[(pairs[estart + i] >> 17) & 255], 1);
    __syncthreads();
    int v = hcnt[t];
    cur[t] = v;
    __syncthreads();
    for (int o = 1; o < 256; o <<= 1) {
        int x = (t >= o) ? cur[t - o] : 0;
        __syncthreads();
        cur[t] += x;
        __syncthreads();
    }
    int excl = cur[t] - v;
    int node = (b << 8) + t;
    if (node < NN) {
        off[node] = estart + excl;
        deg[node] = v;
    }
    __syncthreads();
    cur[t] = estart + excl;
    __syncthreads();
    for (int i = t; i < cnt; i += 256) {
        unsigned int p = pairs[estart + i];
        int pos = atomicAdd(&cur[(p >> 17) & 255], 1);
        ssrc[pos] = (int)(p & 0x1ffffu);
    }
}

// ---------------- fused GEMM epilogue: bf16 features + el/er scores ----------------

__device__ __forceinline__ void epilogue(f32x4 acc[2][8], int row0, int q, int r, int nrows,
                                         const float* __restrict__ al,
                                         const float* __restrict__ ar,
                                         unsigned short* __restrict__ Fb,
                                         float* __restrict__ el, float* __restrict__ er) {
#pragma unroll
    for (int g = 0; g < 2; g++) {
#pragma unroll
        for (int i = 0; i < 4; i++) {
            int row = row0 + g * 16 + q * 4 + i;
            float elp[4], erp[4];
#pragma unroll
            for (int h = 0; h < 4; h++) { elp[h] = 0.f; erp[h] = 0.f; }
#pragma unroll
            for (int nt = 0; nt < 8; nt++) {
                int h = nt >> 1;
                int c = ((nt & 1) << 4) + r;
                float v = acc[g][nt][i];
                elp[h] = fmaf(v, al[h * 32 + c], elp[h]);
                erp[h] = fmaf(v, ar[h * 32 + c], erp[h]);
            }
#pragma unroll
            for (int o = 1; o < 16; o <<= 1) {
#pragma unroll
                for (int h = 0; h < 4; h++) {
                    elp[h] += __shfl_xor(elp[h], o);
                    erp[h] += __shfl_xor(erp[h], o);
                }
            }
            if (row < nrows) {
#pragma unroll
                for (int nt = 0; nt < 8; nt++)
                    Fb[(size_t)row * FD + nt * 16 + r] = f2bf(acc[g][nt][i]);
                int hh = r & 3;
                float ve = (hh & 2) ? ((hh & 1) ? elp[3] : elp[2]) : ((hh & 1) ? elp[1] : elp[0]);
                float vr = (hh & 2) ? ((hh & 1) ? erp[3] : erp[2]) : ((hh & 1) ? erp[1] : erp[0]);
                if (r < 4) el[row * 4 + hh] = ve;
                else if (r < 8) er[row * 4 + hh] = vr;
            }
        }
    }
}

// ---------------- GEMM body (layer 1): A f32, hi/lo split both sides ----------------

__device__ void gemm_f32_body(int bid, const float* __restrict__ A,
                              const unsigned short* __restrict__ Wth,
                              const unsigned short* __restrict__ Wtl,
                              unsigned short* __restrict__ Fb, int nrows,
                              const float* __restrict__ al, const float* __restrict__ ar,
                              float* __restrict__ el, float* __restrict__ er) {
    int t = threadIdx.x;
    int wave = t >> 6, lane = t & 63;
    int r = lane & 15, q = lane >> 4;
    int row0 = bid * 128 + wave * 32;
    int rg0 = row0 + r, rg1 = row0 + 16 + r;

    f32x4 acc[2][8];
#pragma unroll
    for (int g = 0; g < 2; g++)
#pragma unroll
        for (int nt = 0; nt < 8; nt++) acc[g][nt] = (f32x4){0.f, 0.f, 0.f, 0.f};

#pragma unroll
    for (int ks = 0; ks < 4; ks++) {
        int k0 = ks * 32 + q * 8;
        float4 z = make_float4(0.f, 0.f, 0.f, 0.f);
        float4 a0 = z, a1 = z, b0 = z, b1 = z;
        if (rg0 < nrows) {
            const float* pa = A + (size_t)rg0 * FD + k0;
            a0 = *(const float4*)pa;
            a1 = *(const float4*)(pa + 4);
        }
        if (rg1 < nrows) {
            const float* pb = A + (size_t)rg1 * FD + k0;
            b0 = *(const float4*)pb;
            b1 = *(const float4*)(pb + 4);
        }
        bf16x8 ah0, al0, ah1, al1;
        split8(a0, a1, ah0, al0);
        split8(b0, b1, ah1, al1);
#pragma unroll
        for (int nt = 0; nt < 8; nt++) {
            int wo = ((nt * 16 + r) << 7) + k0;
            bf16x8 bh = *(const bf16x8*)(Wth + wo);
            bf16x8 bl = *(const bf16x8*)(Wtl + wo);
            acc[0][nt] = __builtin_amdgcn_mfma_f32_16x16x32_bf16(ah0, bh, acc[0][nt], 0, 0, 0);
            acc[0][nt] = __builtin_amdgcn_mfma_f32_16x16x32_bf16(al0, bh, acc[0][nt], 0, 0, 0);
            acc[0][nt] = __builtin_amdgcn_mfma_f32_16x16x32_bf16(ah0, bl, acc[0][nt], 0, 0, 0);
            acc[1][nt] = __builtin_amdgcn_mfma_f32_16x16x32_bf16(ah1, bh, acc[1][nt], 0, 0, 0);
            acc[1][nt] = __builtin_amdgcn_mfma_f32_16x16x32_bf16(al1, bh, acc[1][nt], 0, 0, 0);
            acc[1][nt] = __builtin_amdgcn_mfma_f32_16x16x32_bf16(ah1, bl, acc[1][nt], 0, 0, 0);
        }
    }
    epilogue(acc, row0, q, r, nrows, al, ar, Fb, el, er);
}

// ---------------- fused dispatch: bsort (blocks 0..NB-1) + layer-1 GEMM (rest) ----------------

__global__ __launch_bounds__(256) void k_sortgemm1(const unsigned int* __restrict__ pairs,
                                                   const int* __restrict__ gcur,
                                                   int* __restrict__ off, int* __restrict__ deg,
                                                   int* __restrict__ ssrc,
                                                   const float* __restrict__ A,
                                                   const unsigned short* __restrict__ Wth,
                                                   const unsigned short* __restrict__ Wtl,
                                                   unsigned short* __restrict__ Fb,
                                                   const float* __restrict__ al,
                                                   const float* __restrict__ ar,
                                                   float* __restrict__ el,
                                                   float* __restrict__ er) {
    int b = blockIdx.x;
    if (b < NB) bsort_body(b, pairs, gcur, off, deg, ssrc);
    else gemm_f32_body(b - NB, A, Wth, Wtl, Fb, NN, al, ar, el, er);
}

// ---------------- MFMA GEMM (layers 2,3): A bf16, W hi/lo -> 2 MFMAs ----------------

__global__ __launch_bounds__(256) void k_gemm_bf(const unsigned short* __restrict__ A,
                                                 const unsigned short* __restrict__ Wth,
                                                 const unsigned short* __restrict__ Wtl,
                                                 unsigned short* __restrict__ Fb, int nrows,
                                                 const float* __restrict__ al,
                                                 const float* __restrict__ ar,
                                                 float* __restrict__ el,
                                                 float* __restrict__ er) {
    int t = threadIdx.x;
    int wave = t >> 6, lane = t & 63;
    int r = lane & 15, q = lane >> 4;
    int row0 = blockIdx.x * 128 + wave * 32;
    int rg0 = row0 + r, rg1 = row0 + 16 + r;

    f32x4 acc[2][8];
#pragma unroll
    for (int g = 0; g < 2; g++)
#pragma unroll
        for (int nt = 0; nt < 8; nt++) acc[g][nt] = (f32x4){0.f, 0.f, 0.f, 0.f};

#pragma unroll
    for (int ks = 0; ks < 4; ks++) {
        int k0 = ks * 32 + q * 8;
        bf16x8 a0 = {0, 0, 0, 0, 0, 0, 0, 0};
        bf16x8 a1 = {0, 0, 0, 0, 0, 0, 0, 0};
        if (rg0 < nrows) a0 = *(const bf16x8*)(A + (size_t)rg0 * FD + k0);
        if (rg1 < nrows) a1 = *(const bf16x8*)(A + (size_t)rg1 * FD + k0);
#pragma unroll
        for (int nt = 0; nt < 8; nt++) {
            int wo = ((nt * 16 + r) << 7) + k0;
            bf16x8 bh = *(const bf16x8*)(Wth + wo);
            bf16x8 bl = *(const bf16x8*)(Wtl + wo);
            acc[0][nt] = __builtin_amdgcn_mfma_f32_16x16x32_bf16(a0, bh, acc[0][nt], 0, 0, 0);
            acc[0][nt] = __builtin_amdgcn_mfma_f32_16x16x32_bf16(a0, bl, acc[0][nt], 0, 0, 0);
            acc[1][nt] = __builtin_amdgcn_mfma_f32_16x16x32_bf16(a1, bh, acc[1][nt], 0, 0, 0);
            acc[1][nt] = __builtin_amdgcn_mfma_f32_16x16x32_bf16(a1, bl, acc[1][nt], 0, 0, 0);
        }
    }
    epilogue(acc, row0, q, r, nrows, al, ar, Fb, el, er);
}

// ---------------- aggregation: one wave per dst node, single pass ----------------

__global__ __launch_bounds__(256) void k_agg(const unsigned short* __restrict__ Fb,
                                             const float* __restrict__ el,
                                             const float* __restrict__ er,
                                             const int* __restrict__ off,
                                             const int* __restrict__ deg_,
                                             const int* __restrict__ ssrc,
                                             unsigned int* __restrict__ outp) {
    int wave = threadIdx.x >> 6;
    int lane = threadIdx.x & 63;
    int d = blockIdx.x * 4 + wave;
    if (d >= NN) return;
    int start = off[d];
    int deg = deg_[d];
    float2 acc = make_float2(0.f, 0.f);
    if (deg > 0) {
        int h = lane & 3;
        int eloc = lane >> 2;
        int hsel = lane >> 4;  // head owning channels {2*lane, 2*lane+1}
        float er_h = er[d * 4 + h];
        float s = 0.f;
        for (int base = 0; base < deg; base += 16) {
            int i = base + eloc;
            float a = 0.f;
            int sid = 0;  // invalid lanes -> row 0 with weight 0 (L1-hot, harmless)
            if (i < deg) {
                sid = ssrc[start + i];
                float v = el[sid * 4 + h] + er_h;
                float e = v > 0.f ? v : 0.2f * v;
                a = __expf(e);
            }
            s += a;
            int sids[16];
            float a16[16];
#pragma unroll
            for (int j = 0; j < 16; j++) {
                sids[j] = __builtin_amdgcn_readlane(sid, 4 * j);
                a16[j] = __shfl(a, 4 * j + hsel, 64);
            }
            unsigned int u[16];
#pragma unroll
            for (int j = 0; j < 16; j++) {
                u[j] = *(const unsigned int*)(Fb + (size_t)sids[j] * FD + lane * 2);
            }
#pragma unroll
            for (int j = 0; j < 16; j++) {
                acc.x = fmaf(a16[j], __uint_as_float(u[j] << 16), acc.x);
                acc.y = fmaf(a16[j], __uint_as_float(u[j] & 0xffff0000u), acc.y);
            }
        }
        for (int o = 4; o < 64; o <<= 1) s += __shfl_xor(s, o);
        float inv = 1.f / __shfl(s, hsel, 64);
        acc.x *= inv;
        acc.y *= inv;
    }
    acc.x = fmaxf(acc.x, 0.f);  // relu
    acc.y = fmaxf(acc.y, 0.f);
    unsigned int pk = ((unsigned int)f2bf(acc.y) << 16) | f2bf(acc.x);
    outp[(size_t)d * 64 + lane] = pk;
}

// ---------------- fused pool + final (last-block pattern) ----------------
// 512 segments -> 65k atomics on 128 addrs (~512-deep): measured harmless.
// Last block re-reads pooled via device-scope atomic loads (cross-XCD safe).

__global__ __launch_bounds__(256) void k_poolfinal(const unsigned int* __restrict__ Hb,
                                                   float* __restrict__ pooled,
                                                   int* __restrict__ done,
                                                   const float* __restrict__ Wfc,
                                                   const float* __restrict__ bfc,
                                                   float* __restrict__ outp) {
    __shared__ int ticket_sh;
    __shared__ float pl[128];
    int t = threadIdx.x;
    int lane = t & 63;           // channel pair {2*lane, 2*lane+1}
    int walker = t >> 6;
    int seg = blockIdx.x * 4 + walker;   // 512 segments over nodes
    const int NSEG = 512;
    int rpn = (NN + NSEG - 1) / NSEG;    // 196
    int r0 = seg * rpn;
    int r1 = min(NN, r0 + rpn);
    float mx = 0.f, my = 0.f;            // post-relu values >= 0
    for (int r = r0; r < r1; ++r) {
        unsigned int u = Hb[(size_t)r * 64 + lane];
        mx = fmaxf(mx, __uint_as_float(u << 16));
        my = fmaxf(my, __uint_as_float(u & 0xffff0000u));
    }
    atomicMax((int*)&pooled[lane * 2], __float_as_int(mx));
    atomicMax((int*)&pooled[lane * 2 + 1], __float_as_int(my));
    __threadfence();
    __syncthreads();
    if (t == 0) ticket_sh = atomicAdd(done, 1);
    __syncthreads();
    if (ticket_sh != 127) return;
    // last block: all 128 blocks' atomics are globally visible
    if (t < 128) {
        int iv = __hip_atomic_load((int*)&pooled[t], __ATOMIC_ACQUIRE, __HIP_MEMORY_SCOPE_AGENT);
        pl[t] = __int_as_float(iv);
    }
    __syncthreads();
    if (t < 64) {
        int j = t & 7;
        int kk = t >> 3;
        float partial = 0.f;
        for (int k = kk * 16; k < kk * 16 + 16; ++k) partial += pl[k] * Wfc[k * 8 + j];
        for (int o = 8; o < 64; o <<= 1) partial += __shfl_xor(partial, o);
        float logit = partial + bfc[j];
        float mxl = logit;
        for (int o = 1; o < 8; o <<= 1) mxl = fmaxf(mxl, __shfl_xor(mxl, o));
        float ex = __expf(logit - mxl);
        float sm = ex;
        for (int o = 1; o < 8; o <<= 1) sm += __shfl_xor(sm, o);
        if (t < 8) outp[t] = ex / sm;
    }
}

// ---------------- launch ----------------

extern "C" void kernel_launch(void* const* d_in, const int* in_sizes, int n_in,
                              void* d_out, int out_size, void* d_ws, size_t ws_size,
                              hipStream_t stream) {
    const float* x   = (const float*)d_in[0];
    const int*   src = (const int*)d_in[1];
    const int*   dst = (const int*)d_in[2];
    const float* W1  = (const float*)d_in[3];
    const float* al1 = (const float*)d_in[4];
    const float* ar1 = (const float*)d_in[5];
    const float* W2  = (const float*)d_in[6];
    const float* al2 = (const float*)d_in[7];
    const float* ar2 = (const float*)d_in[8];
    const float* W3  = (const float*)d_in[9];
    const float* al3 = (const float*)d_in[10];
    const float* ar3 = (const float*)d_in[11];
    const float* Wfc = (const float*)d_in[12];
    const float* bfc = (const float*)d_in[13];
    float* out = (float*)d_out;

    char* p = (char*)d_ws;
    auto alloc = [&](size_t bytes) {
        char* r = p;
        p += (bytes + 255) & ~(size_t)255;
        return r;
    };
    unsigned short* Fb = (unsigned short*)alloc((size_t)NN * FD * 2);
    unsigned int*   Hb = (unsigned int*)alloc((size_t)NN * FD * 2);  // bf16x2-packed H
    float* el     = (float*)alloc((size_t)NN * 4 * 4);
    float* er     = (float*)alloc((size_t)NN * 4 * 4);
    int*   off    = (int*)alloc((size_t)NN * 4);
    int*   deg    = (int*)alloc((size_t)NN * 4);
    int*   ssrc   = (int*)alloc((size_t)NB * CAP * 4);
    unsigned int* pairs = (unsigned int*)alloc((size_t)NB * CAP * 4);
    int*   gcur   = (int*)alloc((size_t)NB * 4);
    float* pooled = (float*)alloc(128 * 4);
    int*   done   = (int*)alloc(256);
    unsigned short* Wth = (unsigned short*)alloc(3 * 16384 * 2);
    unsigned short* Wtl = (unsigned short*)alloc(3 * 16384 * 2);

    const int AB = (NN + 3) / 4;
    const int BB = (NE + CHUNK - 1) / CHUNK;  // 196

    k_wsplit3<<<192, 256, 0, stream>>>(W1, W2, W3, Wth, Wtl, gcur, pooled, done);
    k_bucket<<<BB, 256, 0, stream>>>(src, dst, gcur, pairs);

    // bsort + layer-1 GEMM fused (independent work)
    k_sortgemm1<<<NB + GB, 256, 0, stream>>>(pairs, gcur, off, deg, ssrc,
                                             x, Wth, Wtl, Fb, al1, ar1, el, er);
    k_agg<<<AB, 256, 0, stream>>>(Fb, el, er, off, deg, ssrc, Hb);
    // layer 2
    k_gemm_bf<<<GB, 256, 0, stream>>>((const unsigned short*)Hb, Wth + 16384, Wtl + 16384, Fb, NN, al2, ar2, el, er);
    k_agg<<<AB, 256, 0, stream>>>(Fb, el, er, off, deg, ssrc, Hb);
    // layer 3
    k_gemm_bf<<<GB, 256, 0, stream>>>((const unsigned short*)Hb, Wth + 32768, Wtl + 32768, Fb, NN, al3, ar3, el, er);
    k_agg<<<AB, 256, 0, stream>>>(Fb, el, er, off, deg, ssrc, Hb);

    // pool + final fused (last-block pattern)
    k_poolfinal<<<128, 256, 0, stream>>>(Hb, pooled, done, Wfc, bfc, out);
}